// Round 4
// baseline (431.843 us; speedup 1.0000x reference)
//
#include <hip/hip_runtime.h>
#include <hip/hip_bf16.h>
#include <stdint.h>

// ---------------------------------------------------------------------------
// AttentionActPrune: B=16, S=1024, D=1024, H=16, DH=64.
// Inputs/outputs FP32. Compute: convert to bf16, fused QKV gemm (32x32 MFMA,
// Q pre-scaled by log2(e)/8) -> V transpose -> attention (S^T trick, packed
// P, halved Ps for occupancy) -> out gemm (fp32 out).
// ---------------------------------------------------------------------------

typedef short bf16x8 __attribute__((ext_vector_type(8)));
typedef float f32x4 __attribute__((ext_vector_type(4)));
typedef float f32x16 __attribute__((ext_vector_type(16)));
typedef unsigned short ushort_t;
typedef ushort_t us8 __attribute__((ext_vector_type(8)));

__device__ __forceinline__ ushort_t f2b(float f) {
    unsigned x;
    __builtin_memcpy(&x, &f, 4);
    unsigned r = (x + 0x7fffu + ((x >> 16) & 1u)) >> 16;
    return (ushort_t)r;
}

__device__ __forceinline__ void glds16(const void* g, void* l) {
    __builtin_amdgcn_global_load_lds(
        (const __attribute__((address_space(1))) void*)g,
        (__attribute__((address_space(3))) void*)l, 16, 0, 0);
}

#define MFMA16(a, b, c) __builtin_amdgcn_mfma_f32_16x16x32_bf16((a), (b), (c), 0, 0, 0)
#define MFMA32(a, b, c) __builtin_amdgcn_mfma_f32_32x32x16_bf16((a), (b), (c), 0, 0, 0)

// ---------------------------------------------------------------------------
// fp32 -> bf16 (RNE), 8 elems/thread. grid.y selects among 4 src/dst pairs.
// ---------------------------------------------------------------------------
__global__ __launch_bounds__(256, 8) void cvt4_kernel(
    const float* __restrict__ s0, const float* __restrict__ s1,
    const float* __restrict__ s2, const float* __restrict__ s3,
    ushort_t* __restrict__ d0, ushort_t* __restrict__ d1,
    ushort_t* __restrict__ d2, ushort_t* __restrict__ d3, int n8)
{
    const float* in = (blockIdx.y == 0) ? s0 : (blockIdx.y == 1) ? s1
                       : (blockIdx.y == 2) ? s2 : s3;
    ushort_t* out = (blockIdx.y == 0) ? d0 : (blockIdx.y == 1) ? d1
                       : (blockIdx.y == 2) ? d2 : d3;
    int i = blockIdx.x * 256 + threadIdx.x;
    if (i >= n8) return;
    const float4* p = (const float4*)in + (size_t)i * 2;
    float4 a = p[0], b = p[1];
    us8 v;
    v[0] = f2b(a.x); v[1] = f2b(a.y); v[2] = f2b(a.z); v[3] = f2b(a.w);
    v[4] = f2b(b.x); v[5] = f2b(b.y); v[6] = f2b(b.z); v[7] = f2b(b.w);
    *((us8*)out + i) = v;
}

__global__ __launch_bounds__(256, 8) void cvt1_kernel(
    const float* __restrict__ in, ushort_t* __restrict__ out, int n8)
{
    int i = blockIdx.x * 256 + threadIdx.x;
    if (i >= n8) return;
    const float4* p = (const float4*)in + (size_t)i * 2;
    float4 a = p[0], b = p[1];
    us8 v;
    v[0] = f2b(a.x); v[1] = f2b(a.y); v[2] = f2b(a.z); v[3] = f2b(a.w);
    v[4] = f2b(b.x); v[5] = f2b(b.y); v[6] = f2b(b.z); v[7] = f2b(b.w);
    *((us8*)out + i) = v;
}

// ---------------------------------------------------------------------------
// GEMM with bias+scale: C[m,n] = (sum_k A[m,k]*W[n,k] + bias[n]) * scale
// 32x32x16 MFMA. 128x128 tile, BK=64, 4 waves (2x2), wave = 2x2 of 32x32.
// ---------------------------------------------------------------------------
template <bool OUTF>
__global__ __launch_bounds__(256, 2) void gemm_bias_kernel(
    const ushort_t* __restrict__ A,
    const ushort_t* __restrict__ W0, const ushort_t* __restrict__ W1, const ushort_t* __restrict__ W2,
    const float* __restrict__ b0, const float* __restrict__ b1, const float* __restrict__ b2,
    void* __restrict__ C0, void* __restrict__ C1, void* __restrict__ C2,
    float s0, float s1, float s2,
    int M, int N, int K)
{
    const ushort_t* W = (blockIdx.z == 0) ? W0 : ((blockIdx.z == 1) ? W1 : W2);
    const float* bias = (blockIdx.z == 0) ? b0 : ((blockIdx.z == 1) ? b1 : b2);
    void* C = (blockIdx.z == 0) ? C0 : ((blockIdx.z == 1) ? C1 : C2);
    const float scale = (blockIdx.z == 0) ? s0 : ((blockIdx.z == 1) ? s1 : s2);

    __shared__ ushort_t As[128 * 64];   // [row][k], 16B chunks XOR-8 swizzled
    __shared__ ushort_t Bs[128 * 64];

    const int tid = threadIdx.x;
    const int lane = tid & 63;
    const int wave = tid >> 6;
    const int bm = blockIdx.x * 128;
    const int bn = blockIdx.y * 128;
    const int wm = (wave >> 1) * 64;
    const int wn = (wave & 1) * 64;
    const int r32 = lane & 31;
    const int g = lane >> 5;

    f32x16 acc[2][2] = {};

    for (int k0 = 0; k0 < K; k0 += 64) {
        __syncthreads();
#pragma unroll
        for (int it = 0; it < 4; ++it) {
            int cid = it * 256 + tid;
            int r = cid >> 3;
            int s = cid & 7;
            int sc = s ^ (r & 7);
            glds16(A + (size_t)(bm + r) * K + k0 + sc * 8, As + cid * 8);
            glds16(W + (size_t)(bn + r) * K + k0 + sc * 8, Bs + cid * 8);
        }
        __syncthreads();
#pragma unroll
        for (int kk = 0; kk < 4; ++kk) {
            bf16x8 af[2], bfr[2];
#pragma unroll
            for (int i = 0; i < 2; ++i) {
                int row = wm + i * 32 + r32;
                int ch = (kk * 2 + g) ^ (row & 7);
                af[i] = *(const bf16x8*)(As + row * 64 + ch * 8);
                int rowb = wn + i * 32 + r32;
                int chb = (kk * 2 + g) ^ (rowb & 7);
                bfr[i] = *(const bf16x8*)(Bs + rowb * 64 + chb * 8);
            }
#pragma unroll
            for (int i = 0; i < 2; ++i)
#pragma unroll
                for (int j = 0; j < 2; ++j)
                    acc[i][j] = MFMA32(af[i], bfr[j], acc[i][j]);
        }
    }

    // epilogue: C/D 32x32 layout col=lane&31, row=(reg&3)+8*(reg>>2)+4*g
#pragma unroll
    for (int j = 0; j < 2; ++j) {
        int col = bn + wn + j * 32 + r32;
        float bv = bias[col];
#pragma unroll
        for (int i = 0; i < 2; ++i) {
            int rbase = bm + wm + i * 32 + 4 * g;
#pragma unroll
            for (int reg = 0; reg < 16; ++reg) {
                int row = rbase + (reg & 3) + 8 * (reg >> 2);
                float v = (acc[i][j][reg] + bv) * scale;
                if (OUTF)
                    ((float*)C)[(size_t)row * N + col] = v;
                else
                    ((ushort_t*)C)[(size_t)row * N + col] = f2b(v);
            }
        }
    }
}

// ---------------------------------------------------------------------------
// V transpose: V[b*1024+s][h*64+d] -> Vt[(b*16+h)*64+d][s]  (bf16)
// ---------------------------------------------------------------------------
__global__ __launch_bounds__(256, 4) void transpose_v_kernel(
    const ushort_t* __restrict__ V, ushort_t* __restrict__ Vt)
{
    __shared__ ushort_t t[64 * 65];
    const int bh = blockIdx.x;
    const int st = blockIdx.y;
    const int b = bh >> 4, h = bh & 15;
    const int tid = threadIdx.x;

#pragma unroll
    for (int i = 0; i < 16; ++i) {
        int e = i * 256 + tid;
        int s = e >> 6, d = e & 63;
        t[s * 65 + d] = V[(size_t)(b * 1024 + st * 64 + s) * 1024 + h * 64 + d];
    }
    __syncthreads();
#pragma unroll
    for (int i = 0; i < 16; ++i) {
        int e = i * 256 + tid;
        int d = e >> 6, s = e & 63;
        Vt[(size_t)(bh * 64 + d) * 1024 + st * 64 + s] = t[s * 65 + d];
    }
}

// ---------------------------------------------------------------------------
// Attention v3: per block (bh, qtile of 128 rows). 4 waves x 32 q-rows,
// m-groups processed sequentially (halves Ps -> 25600B LDS -> 6 blocks/CU).
// Q is pre-scaled by log2(e)/sqrt(DH) in the QKV epilogue: p = exp2(z).
// ---------------------------------------------------------------------------
__global__ __launch_bounds__(256, 4) void attn_kernel(
    const ushort_t* __restrict__ Q, const ushort_t* __restrict__ K,
    const ushort_t* __restrict__ Vt, ushort_t* __restrict__ ctx)
{
    __shared__ ushort_t Ks[64 * 64];        // [kv][d] swizzled chunks
    __shared__ ushort_t Vs[64 * 64];        // [d][kv] swizzled chunks
    __shared__ ushort_t Ps[4][16 * 72];     // per-wave P: [m 0..15][k 0..63]

    const int bh = blockIdx.x;   // 0..255
    const int qt = blockIdx.y;   // 0..7
    const int b = bh >> 4, h = bh & 15;
    const int tid = threadIdx.x;
    const int lane = tid & 63;
    const int wave = tid >> 6;
    const int q = lane >> 4;
    const int ml = lane & 15;

    // Q fragments (B operand of S^T mfma)
    bf16x8 qf[2][2];
#pragma unroll
    for (int mg = 0; mg < 2; ++mg) {
        int row = b * 1024 + qt * 128 + wave * 32 + mg * 16 + ml;
        const ushort_t* qp = Q + (size_t)row * 1024 + h * 64;
        qf[mg][0] = *(const bf16x8*)(qp + q * 8);
        qf[mg][1] = *(const bf16x8*)(qp + 32 + q * 8);
    }

    f32x4 o[2][4] = {};
    float l[2] = {0.f, 0.f};
    ushort_t* Pw = Ps[wave];

    for (int kt = 0; kt < 16; ++kt) {
        __syncthreads();
#pragma unroll
        for (int it = 0; it < 2; ++it) {
            int cid = it * 256 + tid;   // 0..511
            int r = cid >> 3, s = cid & 7, sc = s ^ (r & 7);
            glds16(K + (size_t)(b * 1024 + kt * 64 + r) * 1024 + h * 64 + sc * 8,
                   Ks + cid * 8);
            glds16(Vt + (size_t)(bh * 64 + r) * 1024 + kt * 64 + sc * 8,
                   Vs + cid * 8);
        }
        __syncthreads();

#pragma unroll
        for (int mg = 0; mg < 2; ++mg) {
            // S^T = K Q^T: C col=m(=ml), row=k_local=q*4+r (4 consecutive k)
#pragma unroll
            for (int n = 0; n < 4; ++n) {
                int row = n * 16 + ml;
                int c0 = q ^ (row & 7);
                int c1 = (4 + q) ^ (row & 7);
                bf16x8 k0 = *(const bf16x8*)(Ks + row * 64 + c0 * 8);
                bf16x8 k1 = *(const bf16x8*)(Ks + row * 64 + c1 * 8);
                f32x4 z = {};
                z = MFMA16(k0, qf[mg][0], z);
                z = MFMA16(k1, qf[mg][1], z);
                float p0 = exp2f(z[0]);
                float p1 = exp2f(z[1]);
                float p2 = exp2f(z[2]);
                float p3 = exp2f(z[3]);
                l[mg] += (p0 + p1) + (p2 + p3);
                __hip_bfloat162 h01 = __float22bfloat162_rn(make_float2(p0, p1));
                __hip_bfloat162 h23 = __float22bfloat162_rn(make_float2(p2, p3));
                uint2 dd;
                __builtin_memcpy(&dd.x, &h01, 4);
                __builtin_memcpy(&dd.y, &h23, 4);
                *(uint2*)(Pw + ml * 72 + n * 16 + q * 4) = dd;
            }

            // P A-frags: lane ml reads row ml, contiguous k
            bf16x8 pf0 = *(const bf16x8*)(Pw + ml * 72 + q * 8);
            bf16x8 pf1 = *(const bf16x8*)(Pw + ml * 72 + 32 + q * 8);

            // O += P V
#pragma unroll
            for (int n = 0; n < 4; ++n) {
                int row = n * 16 + ml;
                int c0 = q ^ (row & 7);
                int c1 = (4 + q) ^ (row & 7);
                bf16x8 v0 = *(const bf16x8*)(Vs + row * 64 + c0 * 8);
                bf16x8 v1 = *(const bf16x8*)(Vs + row * 64 + c1 * 8);
                o[mg][n] = MFMA16(pf0, v0, o[mg][n]);
                o[mg][n] = MFMA16(pf1, v1, o[mg][n]);
            }
        }
    }

    // row sums: quads partition k in-lane; xor across quad bits completes.
    float li[2];
#pragma unroll
    for (int mg = 0; mg < 2; ++mg) {
        float s = l[mg];
        s += __shfl_xor(s, 16, 64);
        s += __shfl_xor(s, 32, 64);
        li[mg] = 1.0f / s;
    }

    const int orow_base = b * 1024 + qt * 128 + wave * 32;
#pragma unroll
    for (int mg = 0; mg < 2; ++mg) {
#pragma unroll
        for (int r = 0; r < 4; ++r) {
            float lv = __shfl(li[mg], q * 4 + r, 64);
            int orow = orow_base + mg * 16 + q * 4 + r;
#pragma unroll
            for (int n = 0; n < 4; ++n) {
                ctx[(size_t)orow * 1024 + h * 64 + n * 16 + ml] =
                    f2b(o[mg][n][r] * lv);
            }
        }
    }
}

// ---------------------------------------------------------------------------
extern "C" void kernel_launch(void* const* d_in, const int* in_sizes, int n_in,
                              void* d_out, int out_size, void* d_ws, size_t ws_size,
                              hipStream_t stream)
{
    const float* X  = (const float*)d_in[0];
    const float* Wq = (const float*)d_in[1];
    const float* bq = (const float*)d_in[2];
    const float* Wk = (const float*)d_in[3];
    const float* bk = (const float*)d_in[4];
    const float* Wv = (const float*)d_in[5];
    const float* bv = (const float*)d_in[6];
    const float* Wo = (const float*)d_in[7];
    const float* bo = (const float*)d_in[8];

    const int D = 1024;
    const int M = in_sizes[0] / D;       // 16384
    const int Bb = M / 1024;             // 16 batches
    const size_t MD = (size_t)M * D;
    const size_t DD = (size_t)D * D;

    ushort_t* ws  = (ushort_t*)d_ws;
    ushort_t* Xbf = ws;                  // -> reused as Vt after QKV
    ushort_t* Qb  = ws + MD;
    ushort_t* Kb  = ws + 2 * MD;
    ushort_t* Vb  = ws + 3 * MD;         // -> reused as ctx after transpose
    ushort_t* Wqb = ws + 4 * MD;
    ushort_t* Wkb = Wqb + DD;
    ushort_t* Wvb = Wkb + DD;
    ushort_t* Wob = Wvb + DD;
    ushort_t* Vtb = Xbf;
    ushort_t* ctx = Vb;

    dim3 blk(256);

    cvt1_kernel<<<(int)(MD / 8 / 256), blk, 0, stream>>>(X, Xbf, (int)(MD / 8));
    cvt4_kernel<<<dim3((int)(DD / 8 / 256), 4), blk, 0, stream>>>(
        Wq, Wk, Wv, Wo, Wqb, Wkb, Wvb, Wob, (int)(DD / 8));

    // Q pre-scaled by log2(e)/sqrt(64) so attention uses exp2 directly.
    const float qscale = 1.4426950408889634f * 0.125f;
    dim3 gqkv(M / 128, D / 128, 3);
    gemm_bias_kernel<false><<<gqkv, blk, 0, stream>>>(Xbf, Wqb, Wkb, Wvb, bq, bk, bv,
                                                      Qb, Kb, Vb,
                                                      qscale, 1.0f, 1.0f, M, D, D);

    transpose_v_kernel<<<dim3(Bb * 16, 16), blk, 0, stream>>>(Vb, Vtb);

    attn_kernel<<<dim3(Bb * 16, 8), blk, 0, stream>>>(Qb, Kb, Vtb, ctx);

    dim3 go(M / 128, D / 128, 1);
    gemm_bias_kernel<true><<<go, blk, 0, stream>>>(ctx, Wob, Wob, Wob, bo, bo, bo,
                                                   d_out, d_out, d_out,
                                                   1.0f, 1.0f, 1.0f, M, D, D);
}

// Round 5
// 405.595 us; speedup vs baseline: 1.0647x; 1.0647x over previous
//
#include <hip/hip_runtime.h>
#include <hip/hip_bf16.h>
#include <stdint.h>

// ---------------------------------------------------------------------------
// AttentionActPrune: B=16, S=1024, D=1024, H=16, DH=64.
// Inputs/outputs FP32. Compute: convert to bf16, fused QKV gemm (32x32 MFMA,
// Q pre-scaled by log2(e)/8) -> V transpose -> attention v5 (S^T trick,
// double-buffered K/V staging, parallel m-groups, ones-MFMA row sums)
// -> out gemm (fp32 out).
// ---------------------------------------------------------------------------

typedef short bf16x8 __attribute__((ext_vector_type(8)));
typedef float f32x4 __attribute__((ext_vector_type(4)));
typedef float f32x16 __attribute__((ext_vector_type(16)));
typedef unsigned short ushort_t;
typedef ushort_t us8 __attribute__((ext_vector_type(8)));

__device__ __forceinline__ ushort_t f2b(float f) {
    unsigned x;
    __builtin_memcpy(&x, &f, 4);
    unsigned r = (x + 0x7fffu + ((x >> 16) & 1u)) >> 16;
    return (ushort_t)r;
}

__device__ __forceinline__ void glds16(const void* g, void* l) {
    __builtin_amdgcn_global_load_lds(
        (const __attribute__((address_space(1))) void*)g,
        (__attribute__((address_space(3))) void*)l, 16, 0, 0);
}

#define MFMA16(a, b, c) __builtin_amdgcn_mfma_f32_16x16x32_bf16((a), (b), (c), 0, 0, 0)
#define MFMA32(a, b, c) __builtin_amdgcn_mfma_f32_32x32x16_bf16((a), (b), (c), 0, 0, 0)

// ---------------------------------------------------------------------------
// fp32 -> bf16 (RNE), 8 elems/thread. grid.y selects among 4 src/dst pairs.
// ---------------------------------------------------------------------------
__global__ __launch_bounds__(256, 8) void cvt4_kernel(
    const float* __restrict__ s0, const float* __restrict__ s1,
    const float* __restrict__ s2, const float* __restrict__ s3,
    ushort_t* __restrict__ d0, ushort_t* __restrict__ d1,
    ushort_t* __restrict__ d2, ushort_t* __restrict__ d3, int n8)
{
    const float* in = (blockIdx.y == 0) ? s0 : (blockIdx.y == 1) ? s1
                       : (blockIdx.y == 2) ? s2 : s3;
    ushort_t* out = (blockIdx.y == 0) ? d0 : (blockIdx.y == 1) ? d1
                       : (blockIdx.y == 2) ? d2 : d3;
    int i = blockIdx.x * 256 + threadIdx.x;
    if (i >= n8) return;
    const float4* p = (const float4*)in + (size_t)i * 2;
    float4 a = p[0], b = p[1];
    us8 v;
    v[0] = f2b(a.x); v[1] = f2b(a.y); v[2] = f2b(a.z); v[3] = f2b(a.w);
    v[4] = f2b(b.x); v[5] = f2b(b.y); v[6] = f2b(b.z); v[7] = f2b(b.w);
    *((us8*)out + i) = v;
}

__global__ __launch_bounds__(256, 8) void cvt1_kernel(
    const float* __restrict__ in, ushort_t* __restrict__ out, int n8)
{
    int i = blockIdx.x * 256 + threadIdx.x;
    if (i >= n8) return;
    const float4* p = (const float4*)in + (size_t)i * 2;
    float4 a = p[0], b = p[1];
    us8 v;
    v[0] = f2b(a.x); v[1] = f2b(a.y); v[2] = f2b(a.z); v[3] = f2b(a.w);
    v[4] = f2b(b.x); v[5] = f2b(b.y); v[6] = f2b(b.z); v[7] = f2b(b.w);
    *((us8*)out + i) = v;
}

// ---------------------------------------------------------------------------
// GEMM with bias+scale: C[m,n] = (sum_k A[m,k]*W[n,k] + bias[n]) * scale
// 32x32x16 MFMA. 128x128 tile, BK=64, 4 waves (2x2), wave = 2x2 of 32x32.
// ---------------------------------------------------------------------------
template <bool OUTF>
__global__ __launch_bounds__(256, 2) void gemm_bias_kernel(
    const ushort_t* __restrict__ A,
    const ushort_t* __restrict__ W0, const ushort_t* __restrict__ W1, const ushort_t* __restrict__ W2,
    const float* __restrict__ b0, const float* __restrict__ b1, const float* __restrict__ b2,
    void* __restrict__ C0, void* __restrict__ C1, void* __restrict__ C2,
    float s0, float s1, float s2,
    int M, int N, int K)
{
    const ushort_t* W = (blockIdx.z == 0) ? W0 : ((blockIdx.z == 1) ? W1 : W2);
    const float* bias = (blockIdx.z == 0) ? b0 : ((blockIdx.z == 1) ? b1 : b2);
    void* C = (blockIdx.z == 0) ? C0 : ((blockIdx.z == 1) ? C1 : C2);
    const float scale = (blockIdx.z == 0) ? s0 : ((blockIdx.z == 1) ? s1 : s2);

    __shared__ ushort_t As[128 * 64];   // [row][k], 16B chunks XOR-8 swizzled
    __shared__ ushort_t Bs[128 * 64];

    const int tid = threadIdx.x;
    const int lane = tid & 63;
    const int wave = tid >> 6;
    const int bm = blockIdx.x * 128;
    const int bn = blockIdx.y * 128;
    const int wm = (wave >> 1) * 64;
    const int wn = (wave & 1) * 64;
    const int r32 = lane & 31;
    const int g = lane >> 5;

    f32x16 acc[2][2] = {};

    for (int k0 = 0; k0 < K; k0 += 64) {
        __syncthreads();
#pragma unroll
        for (int it = 0; it < 4; ++it) {
            int cid = it * 256 + tid;
            int r = cid >> 3;
            int s = cid & 7;
            int sc = s ^ (r & 7);
            glds16(A + (size_t)(bm + r) * K + k0 + sc * 8, As + cid * 8);
            glds16(W + (size_t)(bn + r) * K + k0 + sc * 8, Bs + cid * 8);
        }
        __syncthreads();
#pragma unroll
        for (int kk = 0; kk < 4; ++kk) {
            bf16x8 af[2], bfr[2];
#pragma unroll
            for (int i = 0; i < 2; ++i) {
                int row = wm + i * 32 + r32;
                int ch = (kk * 2 + g) ^ (row & 7);
                af[i] = *(const bf16x8*)(As + row * 64 + ch * 8);
                int rowb = wn + i * 32 + r32;
                int chb = (kk * 2 + g) ^ (rowb & 7);
                bfr[i] = *(const bf16x8*)(Bs + rowb * 64 + chb * 8);
            }
#pragma unroll
            for (int i = 0; i < 2; ++i)
#pragma unroll
                for (int j = 0; j < 2; ++j)
                    acc[i][j] = MFMA32(af[i], bfr[j], acc[i][j]);
        }
    }

    // epilogue: C/D 32x32 layout col=lane&31, row=(reg&3)+8*(reg>>2)+4*g
#pragma unroll
    for (int j = 0; j < 2; ++j) {
        int col = bn + wn + j * 32 + r32;
        float bv = bias[col];
#pragma unroll
        for (int i = 0; i < 2; ++i) {
            int rbase = bm + wm + i * 32 + 4 * g;
#pragma unroll
            for (int reg = 0; reg < 16; ++reg) {
                int row = rbase + (reg & 3) + 8 * (reg >> 2);
                float v = (acc[i][j][reg] + bv) * scale;
                if (OUTF)
                    ((float*)C)[(size_t)row * N + col] = v;
                else
                    ((ushort_t*)C)[(size_t)row * N + col] = f2b(v);
            }
        }
    }
}

// ---------------------------------------------------------------------------
// V transpose: V[b*1024+s][h*64+d] -> Vt[(b*16+h)*64+d][s]  (bf16)
// ---------------------------------------------------------------------------
__global__ __launch_bounds__(256, 4) void transpose_v_kernel(
    const ushort_t* __restrict__ V, ushort_t* __restrict__ Vt)
{
    __shared__ ushort_t t[64 * 65];
    const int bh = blockIdx.x;
    const int st = blockIdx.y;
    const int b = bh >> 4, h = bh & 15;
    const int tid = threadIdx.x;

#pragma unroll
    for (int i = 0; i < 16; ++i) {
        int e = i * 256 + tid;
        int s = e >> 6, d = e & 63;
        t[s * 65 + d] = V[(size_t)(b * 1024 + st * 64 + s) * 1024 + h * 64 + d];
    }
    __syncthreads();
#pragma unroll
    for (int i = 0; i < 16; ++i) {
        int e = i * 256 + tid;
        int d = e >> 6, s = e & 63;
        Vt[(size_t)(bh * 64 + d) * 1024 + st * 64 + s] = t[s * 65 + d];
    }
}

// ---------------------------------------------------------------------------
// Attention v5: per block (bh, qtile of 128 rows). 4 waves x 32 q-rows
// (parallel m-groups). Double-buffered K/V staging: barrier -> issue next
// tile's glds -> compute current (load latency leaves the critical path;
// the next barrier's vmcnt(0) drain lands after a full compute phase).
// Row sums via MFMA against a constant all-ones B fragment: 1/sum is
// in-lane at row q*4+r, no shuffles. Q pre-scaled by log2(e)/8 upstream.
// ---------------------------------------------------------------------------
__global__ __launch_bounds__(256, 2) void attn_kernel(
    const ushort_t* __restrict__ Q, const ushort_t* __restrict__ K,
    const ushort_t* __restrict__ Vt, ushort_t* __restrict__ ctx)
{
    __shared__ ushort_t Ks[2][64 * 64];     // [kv][d] swizzled chunks
    __shared__ ushort_t Vs[2][64 * 64];     // [d][kv] swizzled chunks
    __shared__ ushort_t Ps[4][32 * 72];     // per-wave P: [m 0..31][k 0..63]

    const int bh = blockIdx.x;   // 0..255
    const int qt = blockIdx.y;   // 0..7
    const int b = bh >> 4, h = bh & 15;
    const int tid = threadIdx.x;
    const int lane = tid & 63;
    const int wave = tid >> 6;
    const int q = lane >> 4;
    const int ml = lane & 15;

    const int cid0 = tid;            // staging chunk ids
    const int cid1 = 256 + tid;
    const int r0 = cid0 >> 3, sc0 = (cid0 & 7) ^ (r0 & 7);
    const int r1 = cid1 >> 3, sc1 = (cid1 & 7) ^ (r1 & 7);
    const ushort_t* Kbase = K + (size_t)(b * 1024) * 1024 + h * 64;
    const ushort_t* Vbase = Vt + (size_t)(bh * 64) * 1024;

    // Q fragments (B operand of S^T mfma)
    bf16x8 qf[2][2];
#pragma unroll
    for (int mg = 0; mg < 2; ++mg) {
        int row = b * 1024 + qt * 128 + wave * 32 + mg * 16 + ml;
        const ushort_t* qp = Q + (size_t)row * 1024 + h * 64;
        qf[mg][0] = *(const bf16x8*)(qp + q * 8);
        qf[mg][1] = *(const bf16x8*)(qp + 32 + q * 8);
    }

    bf16x8 ones;
#pragma unroll
    for (int i = 0; i < 8; ++i) ones[i] = (short)0x3F80;  // bf16 1.0

    f32x4 o[2][4] = {};
    f32x4 ls[2] = {};
    ushort_t* Pw = Ps[wave];

    // prologue: stage kt=0 into buffer 0
    glds16(Kbase + (size_t)r0 * 1024 + sc0 * 8, Ks[0] + cid0 * 8);
    glds16(Vbase + (size_t)r0 * 1024 + sc0 * 8, Vs[0] + cid0 * 8);
    glds16(Kbase + (size_t)r1 * 1024 + sc1 * 8, Ks[0] + cid1 * 8);
    glds16(Vbase + (size_t)r1 * 1024 + sc1 * 8, Vs[0] + cid1 * 8);

    for (int kt = 0; kt < 16; ++kt) {
        const int cur = kt & 1, nxt = cur ^ 1;
        __syncthreads();   // drains this wave's loads for buf[cur]; fences buf[nxt] readers
        if (kt + 1 < 16) {
            const ushort_t* Kn = Kbase + (size_t)(kt + 1) * 64 * 1024;
            const ushort_t* Vn = Vbase + (kt + 1) * 64;
            glds16(Kn + (size_t)r0 * 1024 + sc0 * 8, Ks[nxt] + cid0 * 8);
            glds16(Vn + (size_t)r0 * 1024 + sc0 * 8, Vs[nxt] + cid0 * 8);
            glds16(Kn + (size_t)r1 * 1024 + sc1 * 8, Ks[nxt] + cid1 * 8);
            glds16(Vn + (size_t)r1 * 1024 + sc1 * 8, Vs[nxt] + cid1 * 8);
        }
        const ushort_t* Kc = Ks[cur];
        const ushort_t* Vc = Vs[cur];

        // S^T = K Q^T: C col=m(=ml), row=k_local=q*4+r (4 consecutive k)
#pragma unroll
        for (int n = 0; n < 4; ++n) {
            int row = n * 16 + ml;
            int c0 = q ^ (row & 7);
            int c1 = (4 + q) ^ (row & 7);
            bf16x8 k0 = *(const bf16x8*)(Kc + row * 64 + c0 * 8);
            bf16x8 k1 = *(const bf16x8*)(Kc + row * 64 + c1 * 8);
#pragma unroll
            for (int mg = 0; mg < 2; ++mg) {
                f32x4 z = {};
                z = MFMA16(k0, qf[mg][0], z);
                z = MFMA16(k1, qf[mg][1], z);
                float p0 = __builtin_amdgcn_exp2f(z[0]);
                float p1 = __builtin_amdgcn_exp2f(z[1]);
                float p2 = __builtin_amdgcn_exp2f(z[2]);
                float p3 = __builtin_amdgcn_exp2f(z[3]);
                __hip_bfloat162 h01 = __float22bfloat162_rn(make_float2(p0, p1));
                __hip_bfloat162 h23 = __float22bfloat162_rn(make_float2(p2, p3));
                uint2 dd;
                __builtin_memcpy(&dd.x, &h01, 4);
                __builtin_memcpy(&dd.y, &h23, 4);
                *(uint2*)(Pw + (mg * 16 + ml) * 72 + n * 16 + q * 4) = dd;
            }
        }

        // P A-frags + PV + ones-sum (both m-groups in parallel for ILP)
#pragma unroll
        for (int mg = 0; mg < 2; ++mg) {
            bf16x8 pf0 = *(const bf16x8*)(Pw + (mg * 16 + ml) * 72 + q * 8);
            bf16x8 pf1 = *(const bf16x8*)(Pw + (mg * 16 + ml) * 72 + 32 + q * 8);
            ls[mg] = MFMA16(pf0, ones, ls[mg]);
            ls[mg] = MFMA16(pf1, ones, ls[mg]);
#pragma unroll
            for (int n = 0; n < 4; ++n) {
                int row = n * 16 + ml;
                int c0 = q ^ (row & 7);
                int c1 = (4 + q) ^ (row & 7);
                bf16x8 v0 = *(const bf16x8*)(Vc + row * 64 + c0 * 8);
                bf16x8 v1 = *(const bf16x8*)(Vc + row * 64 + c1 * 8);
                o[mg][n] = MFMA16(pf0, v0, o[mg][n]);
                o[mg][n] = MFMA16(pf1, v1, o[mg][n]);
            }
        }
    }

    // normalize: ls[mg][r] is the full row sum for m=q*4+r (any col) — in-lane.
    const int orow_base = b * 1024 + qt * 128 + wave * 32;
#pragma unroll
    for (int mg = 0; mg < 2; ++mg) {
#pragma unroll
        for (int r = 0; r < 4; ++r) {
            float lv = 1.0f / ls[mg][r];
            int orow = orow_base + mg * 16 + q * 4 + r;
#pragma unroll
            for (int n = 0; n < 4; ++n) {
                ctx[(size_t)orow * 1024 + h * 64 + n * 16 + ml] =
                    f2b(o[mg][n][r] * lv);
            }
        }
    }
}

// ---------------------------------------------------------------------------
extern "C" void kernel_launch(void* const* d_in, const int* in_sizes, int n_in,
                              void* d_out, int out_size, void* d_ws, size_t ws_size,
                              hipStream_t stream)
{
    const float* X  = (const float*)d_in[0];
    const float* Wq = (const float*)d_in[1];
    const float* bq = (const float*)d_in[2];
    const float* Wk = (const float*)d_in[3];
    const float* bk = (const float*)d_in[4];
    const float* Wv = (const float*)d_in[5];
    const float* bv = (const float*)d_in[6];
    const float* Wo = (const float*)d_in[7];
    const float* bo = (const float*)d_in[8];

    const int D = 1024;
    const int M = in_sizes[0] / D;       // 16384
    const int Bb = M / 1024;             // 16 batches
    const size_t MD = (size_t)M * D;
    const size_t DD = (size_t)D * D;

    ushort_t* ws  = (ushort_t*)d_ws;
    ushort_t* Xbf = ws;                  // -> reused as Vt after QKV
    ushort_t* Qb  = ws + MD;
    ushort_t* Kb  = ws + 2 * MD;
    ushort_t* Vb  = ws + 3 * MD;         // -> reused as ctx after transpose
    ushort_t* Wqb = ws + 4 * MD;
    ushort_t* Wkb = Wqb + DD;
    ushort_t* Wvb = Wkb + DD;
    ushort_t* Wob = Wvb + DD;
    ushort_t* Vtb = Xbf;
    ushort_t* ctx = Vb;

    dim3 blk(256);

    cvt1_kernel<<<(int)(MD / 8 / 256), blk, 0, stream>>>(X, Xbf, (int)(MD / 8));
    cvt4_kernel<<<dim3((int)(DD / 8 / 256), 4), blk, 0, stream>>>(
        Wq, Wk, Wv, Wo, Wqb, Wkb, Wvb, Wob, (int)(DD / 8));

    // Q pre-scaled by log2(e)/sqrt(64) so attention uses exp2 directly.
    const float qscale = 1.4426950408889634f * 0.125f;
    dim3 gqkv(M / 128, D / 128, 3);
    gemm_bias_kernel<false><<<gqkv, blk, 0, stream>>>(Xbf, Wqb, Wkb, Wvb, bq, bk, bv,
                                                      Qb, Kb, Vb,
                                                      qscale, 1.0f, 1.0f, M, D, D);

    transpose_v_kernel<<<dim3(Bb * 16, 16), blk, 0, stream>>>(Vb, Vtb);

    attn_kernel<<<dim3(Bb * 16, 8), blk, 0, stream>>>(Qb, Kb, Vtb, ctx);

    dim3 go(M / 128, D / 128, 1);
    gemm_bias_kernel<true><<<go, blk, 0, stream>>>(ctx, Wob, Wob, Wob, bo, bo, bo,
                                                   d_out, d_out, d_out,
                                                   1.0f, 1.0f, 1.0f, M, D, D);
}